// Round 19
// baseline (175.922 us; speedup 1.0000x reference)
//
#include <hip/hip_runtime.h>

// Locally-connected 2x2 conv, unshared weights.
// x: [256 planes, 512, 512] f32; weights: [511*511, 4]; bias: [511*511]
// out: [256, 511, 511]; out row 0 / col 0 are zero.
// neuron index = 511*w + h == flat in-plane output index.
//
// v19 = v16's winning regime (pinned weights, nt full-line stores, per-XCD
// contiguous plane chunks) widened to 8 OUTPUTS/THREAD:
//   reads  20 floats / 8 outputs (2.5/out, was 3.0) -- -17% logical reads
//   VMEM   6 instrs / 8 outputs (was 8)             -- -25% instructions
// Border outputs are folded into the pinned weights (border => w=b=0 =>
// computed zero), so the inner loop has no border masks. Row crossings use
// the flat-layout wrap (x index shifts by +1 crossing a row), as in v16.
// 16 plane-phases: p0=(q&7)*32+(q>>3)*16 keeps XCD q%8 with a contiguous
// 32-plane region per XCD. grid(16,128)=2048 blocks.

typedef float f4u __attribute__((ext_vector_type(4), aligned(4)));
typedef float f2u __attribute__((ext_vector_type(2), aligned(4)));

constexpr int PLANE_OUT = 511 * 511;    // 261121
constexpr int PLANE_IN  = 512 * 512;    // 262144

__global__ __launch_bounds__(256, 7)
void lc_conv2x2_v19(const float* __restrict__ x,
                    const float4* __restrict__ weights,
                    const float* __restrict__ bias,
                    float* __restrict__ out, int planes) {
    const int q = blockIdx.x;           // 0..15 plane phase; XCD = q%8
    const int b = blockIdx.y;           // 0..127
    const int t = threadIdx.x;

    const int chunk = planes >> 4;      // 16 planes per phase
    const int p0 = (q & 7) * 2 * chunk + (q >> 3) * chunk;  // contiguous per XCD

    const int o0 = (b << 11) | (t << 3);        // 8 outputs per thread
    if (o0 > PLANE_OUT - 1) return;             // b=127, t>128

    if (o0 == PLANE_OUT - 1) {                  // single tail output (510,510)
        const float4 wt = weights[PLANE_OUT - 1];
        const float  bv = bias[PLANE_OUT - 1];
        for (int i = 0; i < chunk; ++i) {
            const float* xp = x + (size_t)(p0 + i) * PLANE_IN;
            float v = xp[509 * 512 + 509] * wt.x + xp[509 * 512 + 510] * wt.y
                    + xp[510 * 512 + 509] * wt.z + xp[510 * 512 + 510] * wt.w + bv;
            out[(size_t)(p0 + i) * PLANE_OUT + (PLANE_OUT - 1)] = v;
        }
        return;
    }

    if (o0 <= 504) {                            // outputs 0..511: all borders
        const f4u z = {0.0f, 0.0f, 0.0f, 0.0f};
        for (int i = 0; i < chunk; ++i) {
            float* op = out + (size_t)(p0 + i) * PLANE_OUT + o0;
            __builtin_nontemporal_store(z, (f4u*)op);
            __builtin_nontemporal_store(z, (f4u*)(op + 4));
        }
        return;
    }

    const int w  = o0 / 511;                    // w >= 1 here
    const int h  = o0 - w * 511;
    const int tb = o0 + w - 513;                // flat(w-1, h-1) -- >= 0
    const int bb = tb + 512;

    // crossing predicates (plane-invariant): output j crosses into row w+1
    bool cj[8];
    #pragma unroll
    for (int j = 0; j < 8; ++j) cj[j] = (h + j >= 511);

    // ---- weights/bias -> registers ONCE; borders folded to zero weights
    float wX[8], wY[8], wZ[8], wW[8], bR[8];
    const f4u ba = *(const f4u*)(bias + o0);
    const f4u bb4 = *(const f4u*)(bias + o0 + 4);
    const float braw[8] = {ba.x, ba.y, ba.z, ba.w, bb4.x, bb4.y, bb4.z, bb4.w};
    #pragma unroll
    for (int j = 0; j < 8; ++j) {
        const bool border = (h + j == 511) || (h + j == 0);   // col-0 outputs
        const float4 wt = weights[o0 + j];
        wX[j] = border ? 0.0f : wt.x;
        wY[j] = border ? 0.0f : wt.y;
        wZ[j] = border ? 0.0f : wt.z;
        wW[j] = border ? 0.0f : wt.w;
        bR[j] = border ? 0.0f : braw[j];
    }
    // asm pins (two blocks, <=20 operands each): forbid rematerialization
    asm volatile(""
        : "+v"(wX[0]), "+v"(wX[1]), "+v"(wX[2]), "+v"(wX[3]),
          "+v"(wX[4]), "+v"(wX[5]), "+v"(wX[6]), "+v"(wX[7]),
          "+v"(wY[0]), "+v"(wY[1]), "+v"(wY[2]), "+v"(wY[3]),
          "+v"(wY[4]), "+v"(wY[5]), "+v"(wY[6]), "+v"(wY[7]),
          "+v"(bR[0]), "+v"(bR[1]), "+v"(bR[2]), "+v"(bR[3]));
    asm volatile(""
        : "+v"(wZ[0]), "+v"(wZ[1]), "+v"(wZ[2]), "+v"(wZ[3]),
          "+v"(wZ[4]), "+v"(wZ[5]), "+v"(wZ[6]), "+v"(wZ[7]),
          "+v"(wW[0]), "+v"(wW[1]), "+v"(wW[2]), "+v"(wW[3]),
          "+v"(wW[4]), "+v"(wW[5]), "+v"(wW[6]), "+v"(wW[7]),
          "+v"(bR[4]), "+v"(bR[5]), "+v"(bR[6]), "+v"(bR[7]));

    #pragma unroll 4
    for (int i = 0; i < chunk; ++i) {
        const int p = p0 + i;                   // contiguous per-XCD sweep
        const float* xp = x + (size_t)p * PLANE_IN;

        f4u T0 = *(const f4u*)(xp + tb);        // top row: 10 floats
        f4u T1 = *(const f4u*)(xp + tb + 4);
        f2u T2 = *(const f2u*)(xp + tb + 8);
        f4u B0 = *(const f4u*)(xp + bb);        // bottom row: 10 floats
        f4u B1 = *(const f4u*)(xp + bb + 4);
        f2u B2 = *(const f2u*)(xp + bb + 8);
        const float tv[10] = {T0.x, T0.y, T0.z, T0.w, T1.x, T1.y, T1.z, T1.w, T2.x, T2.y};
        const float bw[10] = {B0.x, B0.y, B0.z, B0.w, B1.x, B1.y, B1.z, B1.w, B2.x, B2.y};

        f4u r0, r1;
        #pragma unroll
        for (int j = 0; j < 8; ++j) {           // static indices; cj -> cndmask
            const float xtl = cj[j] ? tv[j + 1] : tv[j];
            const float xtr = cj[j] ? tv[j + 2] : tv[j + 1];
            const float xbl = cj[j] ? bw[j + 1] : bw[j];
            const float xbr = cj[j] ? bw[j + 2] : bw[j + 1];
            const float v = xtl * wX[j] + xtr * wY[j]
                          + xbl * wZ[j] + xbr * wW[j] + bR[j];
            if (j < 4) r0[j] = v; else r1[j - 4] = v;
        }
        float* op = out + (size_t)p * PLANE_OUT + o0;
        __builtin_nontemporal_store(r0, (f4u*)op);      // two full-line nt stores
        __builtin_nontemporal_store(r1, (f4u*)(op + 4));
    }
}

extern "C" void kernel_launch(void* const* d_in, const int* in_sizes, int n_in,
                              void* d_out, int out_size, void* d_ws, size_t ws_size,
                              hipStream_t stream) {
    const float*  x       = (const float*)d_in[0];
    const float4* weights = (const float4*)d_in[1];
    const float*  bias    = (const float*)d_in[2];
    float*        out     = (float*)d_out;

    int planes = in_sizes[0] / PLANE_IN;        // 256
    dim3 grid(16, 128);                         // 2048 blocks; XCD = q%8
    lc_conv2x2_v19<<<grid, 256, 0, stream>>>(x, weights, bias, out, planes);
}

// Round 20
// 100.867 us; speedup vs baseline: 1.7441x; 1.7441x over previous
//
#include <hip/hip_runtime.h>

// Locally-connected 2x2 conv, unshared weights.
// x: [256 planes, 512, 512] f32; weights: [511*511, 4]; bias: [511*511]
// out: [256, 511, 511]; out row 0 / col 0 are zero.
// neuron index = 511*w + h == flat in-plane output index.
//
// v20 = v16 verbatim (best: 101.2us). Reverts v19's 8-out widening, whose
// 32B-lane-stride nt stores were half-dense PER INSTRUCTION -> nt partial
// -line flushes -> WRITE 270->382MB (nt requires single-instruction lane
// density; v4's lesson, milder form).
// Final form: 4 outputs/thread flat-index, aligned dwordx4-class loads,
// single lane-dense dwordx4 nt store (out never allocates in L2/L3),
// asm-pinned weights/bias (compiler otherwise re-loads them per iteration),
// per-XCD contiguous 32-plane chunks (8 phases, XCD = blockIdx.x under %8),
// linear plane sweep. Measured: 425MB/call at ~4.2TB/s effective -- the
// mixed read/write fabric rate observed across all dense variants.

typedef float f4u __attribute__((ext_vector_type(4), aligned(4)));
typedef float f2u __attribute__((ext_vector_type(2), aligned(4)));

constexpr int PLANE_OUT = 511 * 511;    // 261121
constexpr int PLANE_IN  = 512 * 512;    // 262144
constexpr int PSTRIDE   = 8;            // plane phases == XCD count

__global__ __launch_bounds__(256, 7)    // 72 VGPR budget; 28 waves/CU
void lc_conv2x2_v20(const float* __restrict__ x,
                    const float4* __restrict__ weights,
                    const float* __restrict__ bias,
                    float* __restrict__ out, int planes) {
    const int q = blockIdx.x;           // 0..7 plane phase == XCD
    const int b = blockIdx.y;           // 0..255
    const int t = threadIdx.x;

    const int NQ = planes >> 3;         // 32 planes per phase
    const int p0 = q * NQ;              // contiguous chunk [p0, p0+NQ)

    if (b == 255) {                     // tail block: single output o = 261120
        if (t != 0) return;             // (w,h) = (510,510)
        const float4 wt = weights[PLANE_OUT - 1];
        const float  bv = bias[PLANE_OUT - 1];
        for (int i = 0; i < NQ; ++i) {
            const int p = p0 + i;
            const float* xp = x + (size_t)p * PLANE_IN;
            float v = xp[509 * 512 + 509] * wt.x + xp[509 * 512 + 510] * wt.y
                    + xp[510 * 512 + 509] * wt.z + xp[510 * 512 + 510] * wt.w + bv;
            out[(size_t)p * PLANE_OUT + (PLANE_OUT - 1)] = v;
        }
        return;
    }

    const int o0 = (b << 10) | (t << 2);        // 0..261116, multiple of 4
    const int w  = o0 / 511;                    // hoisted magic-div
    const int h  = o0 - w * 511;

    // plane-invariant per-j predicates: crossing + force-zero (borders)
    bool cj[4], zj[4];
    #pragma unroll
    for (int j = 0; j < 4; ++j) {
        const int hr = h + j;
        cj[j] = (hr >= 511);                    // crosses into row w+1
        const int wj = w + (cj[j] ? 1 : 0);
        const int hj = hr - (cj[j] ? 511 : 0);
        zj[j] = (wj == 0) || (hj == 0);         // row-0 / col-0 border
    }

    // ---- weights/bias -> registers ONCE; asm pin forbids rematerialization
    const float4 q0 = weights[o0],     q1 = weights[o0 + 1];
    const float4 q2 = weights[o0 + 2], q3 = weights[o0 + 3];
    const f4u    bq = *(const f4u*)(bias + o0);
    float w0x = q0.x, w0y = q0.y, w0z = q0.z, w0w = q0.w;
    float w1x = q1.x, w1y = q1.y, w1z = q1.z, w1w = q1.w;
    float w2x = q2.x, w2y = q2.y, w2z = q2.z, w2w = q2.w;
    float w3x = q3.x, w3y = q3.y, w3z = q3.z, w3w = q3.w;
    float b0 = bq.x, b1 = bq.y, b2 = bq.z, b3 = bq.w;
    asm volatile(""
        : "+v"(w0x), "+v"(w0y), "+v"(w0z), "+v"(w0w),
          "+v"(w1x), "+v"(w1y), "+v"(w1z), "+v"(w1w),
          "+v"(w2x), "+v"(w2y), "+v"(w2z), "+v"(w2w),
          "+v"(w3x), "+v"(w3y), "+v"(w3z), "+v"(w3w),
          "+v"(b0), "+v"(b1), "+v"(b2), "+v"(b3));
    const float wX[4] = {w0x, w1x, w2x, w3x};
    const float wY[4] = {w0y, w1y, w2y, w3y};
    const float wZ[4] = {w0z, w1z, w2z, w3z};
    const float wW[4] = {w0w, w1w, w2w, w3w};
    const float bR[4] = {b0, b1, b2, b3};

    // x bases: top-left of output o0 = flat(w-1, h-1) = o0 + w - 513
    int tb = o0 + w - 513;
    if (tb < 0) tb = 0;                         // w==0 rows are forced zero anyway
    const int bb = tb + 512;

    #pragma unroll 4
    for (int i = 0; i < NQ; ++i) {
        const int p = p0 + i;                   // contiguous per-XCD sweep
        const float* xp = x + (size_t)p * PLANE_IN;

        f4u T0 = *(const f4u*)(xp + tb);        // top row: 6 floats
        f2u T1 = *(const f2u*)(xp + tb + 4);
        f4u B0 = *(const f4u*)(xp + bb);        // bottom row: 6 floats
        f2u B1 = *(const f2u*)(xp + bb + 4);
        const float tv[6] = {T0.x, T0.y, T0.z, T0.w, T1.x, T1.y};
        const float bv[6] = {B0.x, B0.y, B0.z, B0.w, B1.x, B1.y};

        f4u r;
        #pragma unroll
        for (int j = 0; j < 4; ++j) {           // static indices; cj -> cndmask
            const float xtl = cj[j] ? tv[j + 1] : tv[j];
            const float xtr = cj[j] ? tv[j + 2] : tv[j + 1];
            const float xbl = cj[j] ? bv[j + 1] : bv[j];
            const float xbr = cj[j] ? bv[j + 2] : bv[j + 1];
            const float v = xtl * wX[j] + xtr * wY[j]
                          + xbl * wZ[j] + xbr * wW[j] + bR[j];
            r[j] = zj[j] ? 0.0f : v;
        }
        // single lane-dense dwordx4 nt store: out never allocates in L2/L3
        __builtin_nontemporal_store(r, (f4u*)(out + (size_t)p * PLANE_OUT + o0));
    }
}

extern "C" void kernel_launch(void* const* d_in, const int* in_sizes, int n_in,
                              void* d_out, int out_size, void* d_ws, size_t ws_size,
                              hipStream_t stream) {
    const float*  x       = (const float*)d_in[0];
    const float4* weights = (const float4*)d_in[1];
    const float*  bias    = (const float*)d_in[2];
    float*        out     = (float*)d_out;

    int planes = in_sizes[0] / PLANE_IN;        // 256
    dim3 grid(PSTRIDE, 256);                    // XCD = blockIdx.x under %8
    lc_conv2x2_v20<<<grid, 256, 0, stream>>>(x, weights, bias, out, planes);
}